// Round 5
// baseline (5696.741 us; speedup 1.0000x reference)
//
#include <hip/hip_runtime.h>
#include <hip/hip_bf16.h>
#include <math.h>

#define NB 32
#define HH 512
#define NIN 17
#define NF 12
#define TDIM 24
#define NTRI 3
#define GTOT 72
#define NBLK 224
#define DTC 0.1f
#define SNLC 1.41421356237309515f
#define THETAC 0.5f
#define SCC 0.009765625f
#define EPSC 1e-6f

typedef __hip_bfloat16 bf16;
typedef __attribute__((ext_vector_type(8))) unsigned short ushort8v;

// ---- agent-scope coherent accessors (compiler-generated cache ops) ----
__device__ inline float lda(const float* p) {
  return __hip_atomic_load(p, __ATOMIC_RELAXED, __HIP_MEMORY_SCOPE_AGENT);
}
__device__ inline void sta(float* p, float v) {
  __hip_atomic_store(p, v, __ATOMIC_RELAXED, __HIP_MEMORY_SCOPE_AGENT);
}
__device__ inline unsigned long long ld8u(const float* p) {
  return __hip_atomic_load((const unsigned long long*)p, __ATOMIC_RELAXED, __HIP_MEMORY_SCOPE_AGENT);
}
__device__ inline float u8lo(unsigned long long v) { return __uint_as_float((unsigned)v); }
__device__ inline float u8hi(unsigned long long v) { return __uint_as_float((unsigned)(v >> 32)); }
__device__ inline void st8(float* p, float lo, float hi) {
  unsigned long long v = ((unsigned long long)__float_as_uint(hi) << 32) | (unsigned long long)__float_as_uint(lo);
  __hip_atomic_store((unsigned long long*)p, v, __ATOMIC_RELAXED, __HIP_MEMORY_SCOPE_AGENT);
}

struct Args {
  const float *X, *Y, *A, *RH0;
  const float *Wihp, *Whhp, *Bp, *Wh2hp, *Wihh, *Wh2hh, *Lp, *We, *Be, *Wpe, *Bpe, *Wo, *Bo;
  bf16 *A0T;                                   // [NB][512][512] (RO, cached)
  float *WThh, *WTpp, *WTph, *WTe;             // [512][512] transposed (RO, cached)
  float *WTih_h, *WTih_p;                      // [17][512] (RO, cached)
  float *rh;    // [3][NB][512]  CROSS (coherent)
  float *rp;    // [2][NB][512]  CROSS (coherent)
  float *h1;    // [2][NB][512]  CROSS (coherent)
  float *Wp;    // [NB][512]     block-private (cached)
  float *FU;    // [72][NB][512] block-private (cached)
  float *FV;    // [72][NB][512] block-private (cached)
  float *alpha; // [NB][72]      CROSS (coherent)
  float *gpart; // [3][NB][4][512] CROSS (coherent)
  float *hepart;// [NB][8][512]  CROSS (coherent)
  float *stats; // [2][NB][2]    CROSS (coherent)
  float *sigv;  // [NB]          CROSS (coherent)
  float *rwb;   // [2][NB]       CROSS (coherent)
  float *aselb; // [2][NB][4]    CROSS (coherent)
  float *slog;  // [NB][4]       block-private (cached)
  float *sprob; // [NB][4]       block-private (cached)
  float *out;
  int   *gcnt;  // 8 barrier counters, 64B apart
};

__device__ inline float get_cdec(const Args& a) {
  float lv = fminf(a.Lp[0], 6.0f);
  float sig = 1.0f / (1.0f + expf(lv));
  float decay = fmaxf(-sig, -10.0f);
  return 1.0f + DTC * decay;
}

__device__ inline float blocksum(float v, float* lds4) {
  const int lane = threadIdx.x & 63, wv = threadIdx.x >> 6;
  #pragma unroll
  for (int off = 32; off > 0; off >>= 1) v += __shfl_down(v, off, 64);
  if (lane == 0) lds4[wv] = v;
  __syncthreads();
  float r = lds4[0] + lds4[1] + lds4[2] + lds4[3];
  __syncthreads();
  return r;
}

// fence-free grid barrier (data travels via agent-scope accesses)
__device__ inline void gridbar(int* cnt, int slot, int target) {
  asm volatile("s_waitcnt vmcnt(0)" ::: "memory");
  __syncthreads();
  if (threadIdx.x == 0) {
    __hip_atomic_fetch_add(&cnt[slot*16], 1, __ATOMIC_RELAXED, __HIP_MEMORY_SCOPE_AGENT);
    int s;
    do {
      s = 0;
      #pragma unroll
      for (int q = 0; q < 8; q++)
        s += __hip_atomic_load(&cnt[q*16], __ATOMIC_RELAXED, __HIP_MEMORY_SCOPE_AGENT);
      if (s < target) __builtin_amdgcn_s_sleep(8);
    } while (s < target);
  }
  __syncthreads();
}

// ---------- prep: tiled transpose ----------
__global__ __launch_bounds__(256) void k_prep_t(Args a) {
  __shared__ float tile[32][33];
  const int bid = blockIdx.x, tid = threadIdx.x;
  const float* src; float* dstF = nullptr; bf16* dstB = nullptr; int tIdx;
  if (bid < 8192) {
    int b = bid >> 8; tIdx = bid & 255;
    src = a.A + (size_t)b*HH*HH;
    dstB = a.A0T + (size_t)b*HH*HH;
  } else {
    int m = (bid - 8192) >> 8; tIdx = bid & 255;
    src  = (m == 0) ? a.Wh2hh : (m == 1) ? a.Whhp : (m == 2) ? a.Wh2hp : a.We;
    dstF = (m == 0) ? a.WThh  : (m == 1) ? a.WTpp : (m == 2) ? a.WTph  : a.WTe;
  }
  const int tx = tIdx & 15, ty = tIdx >> 4;
  for (int k = 0; k < 4; k++) {
    int e = tid + k*256, r = e >> 5, c = e & 31;
    tile[r][c] = src[(size_t)(ty*32 + r)*HH + tx*32 + c];
  }
  __syncthreads();
  for (int k = 0; k < 4; k++) {
    int e = tid + k*256, r = e >> 5, c = e & 31;
    float v = tile[c][r];
    size_t off = (size_t)(tx*32 + r)*HH + ty*32 + c;
    if (dstB) dstB[off] = __float2bfloat16(v);
    else      dstF[off] = v;
  }
}

// ---------- prep: rowsums, init state, small transposes, zeros ----------
__global__ __launch_bounds__(256) void k_prep_i(Args a) {
  __shared__ float sacc[16][128];
  __shared__ float lds4[4];
  const int bid = blockIdx.x, tid = threadIdx.x;
  if (bid < 128) {
    const int b = bid >> 2, q = bid & 3, i0 = q*128;
    const int jg = tid >> 4, il = (tid & 15)*8;
    const ushort8v* ap = (const ushort8v*)(a.A0T + (size_t)b*HH*HH);
    const int ci = (i0 + il) >> 3;
    float acc[8] = {0.f,0.f,0.f,0.f,0.f,0.f,0.f,0.f};
    for (int it = 0; it < 32; it++) {
      int j = jg*32 + it;
      ushort8v u = ap[(size_t)j*64 + ci];
      #pragma unroll
      for (int qq = 0; qq < 8; qq++)
        acc[qq] += __uint_as_float(((unsigned)u[qq]) << 16);
    }
    ((float4*)&sacc[jg][il])[0] = make_float4(acc[0],acc[1],acc[2],acc[3]);
    ((float4*)&sacc[jg][il])[1] = make_float4(acc[4],acc[5],acc[6],acc[7]);
    __syncthreads();
    if (tid < 128) {
      float s = 0.f;
      #pragma unroll
      for (int r = 0; r < 16; r++) s += sacc[r][tid];
      a.Wp[b*HH + i0 + tid] = s;
    }
  } else if (bid < 160) {
    const int b = bid - 128;
    const float* r0 = a.RH0 + (size_t)b*HH;
    float s = 0.f, s2 = 0.f;
    for (int ii = tid; ii < HH; ii += 256) {
      float v = r0[ii]; a.rh[b*HH + ii] = v; s += v; s2 += v*v;
    }
    float m  = blocksum(s, lds4) / (float)HH;
    float e2 = blocksum(s2, lds4) / (float)HH;
    if (tid == 0) { a.stats[b*2] = m; a.stats[b*2 + 1] = sqrtf(e2 - m*m + EPSC); }
  } else if (bid == 160) {
    for (int e = tid; e < NB*HH; e += 256) a.rp[e] = 0.f;
    if (tid < NB*4) { a.slog[tid] = 0.f; a.sprob[tid] = 0.f; a.aselb[tid] = 0.f; }
    if (tid < NB) a.rwb[tid] = 0.f;
    if (tid < 8) a.gcnt[tid*16] = 0;
  } else {
    const int m = bid - 161;
    const float* W = m ? a.Wihp : a.Wihh;
    float* D = m ? a.WTih_p : a.WTih_h;
    for (int e = tid; e < NIN*HH; e += 256) {
      int j = e / HH, i = e % HH;
      D[j*HH + i] = W[i*NIN + j];
    }
  }
}

// ---------- persistent loop: batched agent-atomic comm, private FV/alpha ----------
__global__ __launch_bounds__(256) void k_loop(Args a) {
  const int bid = blockIdx.x, tid = threadIdx.x;
  __shared__ float rh_l[HH];
  __shared__ float al_l[GTOT];
  __shared__ float sacc[16][128];
  __shared__ float lds4[4];
  __shared__ float vl[128*33];
  __shared__ float inpA[NB][NIN];
  __shared__ float redm[28];
  __shared__ float rhn_l[HH];
  const int slot = bid & 7;
  const float cdec = get_cdec(a);

  for (int g = 0; g < GTOT; g++) {
    const int t = g % TDIM, tri = g / TDIM;
    // ================= phase 1 =================
    if (bid < 128) {
      const int b = bid >> 2, q4 = bid & 3, i0 = q4*128;
      const float* rhc = a.rh + (size_t)(g % 3)*NB*HH + b*HH;
      // batched hoisted coherent loads (issued back-to-back, waits at first use)
      unsigned long long rhu = ld8u(rhc + 2*tid);
      float av = 0.f;
      if (tid < g) av = lda(a.alpha + b*GTOT + tid);
      float he0[8], he1[8];
      float m_cur = 0.f, sd_cur = 1.f, m_pre = 0.f, sd_pre = 1.f, s_sg = 0.f, h1p = 0.f;
      if (g > 0) {
        #pragma unroll
        for (int q = 0; q < 8; q++) he0[q] = lda(a.hepart + ((size_t)b*8 + q)*HH + tid);
        #pragma unroll
        for (int q = 0; q < 8; q++) he1[q] = lda(a.hepart + ((size_t)b*8 + q)*HH + tid + 256);
        unsigned long long sc = ld8u(a.stats + (g & 1)*NB*2 + b*2);
        unsigned long long sp = ld8u(a.stats + ((g + 1) & 1)*NB*2 + b*2);
        m_cur = u8lo(sc); sd_cur = u8hi(sc);
        m_pre = u8lo(sp); sd_pre = u8hi(sp);
        s_sg = lda(a.sigv + b);
        if (tid < 128) h1p = lda(a.h1 + (size_t)((g + 1) & 1)*NB*HH + b*HH + i0 + tid);
      }
      rh_l[2*tid]     = u8lo(rhu);
      rh_l[2*tid + 1] = u8hi(rhu);
      if (tid < g) al_l[tid] = av;
      __syncthreads();
      float ev = 0.f;
      if (g > 0) {
        float part = 0.f;
        {
          float hv = a.Be[tid];
          #pragma unroll
          for (int q = 0; q < 8; q++) hv += he0[q];
          part += a.Wpe[tid] * fmaxf(hv, 0.f);
        }
        {
          float hv = a.Be[tid + 256];
          #pragma unroll
          for (int q = 0; q < 8; q++) hv += he1[q];
          part += a.Wpe[tid + 256] * fmaxf(hv, 0.f);
        }
        float pe = blocksum(part, lds4) + a.Bpe[0];
        ev = 0.01f / (1.0f + expf(-pe));
      }
      // wide A0T matvec (cached, L2-resident)
      const int jg = tid >> 4, il = (tid & 15)*8;
      const ushort8v* ap = (const ushort8v*)(a.A0T + (size_t)b*HH*HH);
      const int ci = (i0 + il) >> 3;
      float acc[8] = {0.f,0.f,0.f,0.f,0.f,0.f,0.f,0.f};
      for (int it = 0; it < 32; it++) {
        int j = jg*32 + it;
        ushort8v u = ap[(size_t)j*64 + ci];
        float w = rh_l[j];
        #pragma unroll
        for (int qq = 0; qq < 8; qq++)
          acc[qq] = fmaf(__uint_as_float(((unsigned)u[qq]) << 16), w, acc[qq]);
      }
      // FU history fold (block-private, cached)
      for (int s = jg; s < g - 1; s += 16) {
        const float4* fp = (const float4*)(a.FU + (size_t)(s*NB + b)*HH + i0 + il);
        float4 f0 = fp[0], f1 = fp[1];
        float al = al_l[s];
        acc[0] = fmaf(f0.x, al, acc[0]); acc[1] = fmaf(f0.y, al, acc[1]);
        acc[2] = fmaf(f0.z, al, acc[2]); acc[3] = fmaf(f0.w, al, acc[3]);
        acc[4] = fmaf(f1.x, al, acc[4]); acc[5] = fmaf(f1.y, al, acc[5]);
        acc[6] = fmaf(f1.z, al, acc[6]); acc[7] = fmaf(f1.w, al, acc[7]);
      }
      ((float4*)&sacc[jg][il])[0] = make_float4(acc[0],acc[1],acc[2],acc[3]);
      ((float4*)&sacc[jg][il])[1] = make_float4(acc[4],acc[5],acc[6],acc[7]);
      __syncthreads();
      if (tid < 128) {
        const int i = i0 + tid;
        float colsum = 0.f;
        #pragma unroll
        for (int r = 0; r < 16; r++) colsum += sacc[r][tid];
        if (g > 0) {
          float wpv = a.Wp[b*HH + i];
          float wv  = powf(cdec, (float)(g - 1)) * wpv;
          float tmp = (h1p - m_pre*wv) / sd_pre;
          float post = (rh_l[i] - m_cur) / sd_cur;
          float coef = powf(cdec, -(float)g) * DTC * ev;
          float fu = coef * (post - tmp);
          a.FU[(size_t)((g - 1)*NB + b)*HH + i] = fu;
          a.Wp[b*HH + i] = wpv + s_sg * fu;
          colsum += al_l[g - 1] * fu;
        }
        sta(a.h1 + (size_t)(g & 1)*NB*HH + b*HH + i, powf(cdec, (float)g) * colsum);
      }
    } else {
      // batch-tiled GEMM partials (weights cached; vec/out via paired atomics)
      const int gid = bid - 128;
      const int m = gid >> 5, sub = gid & 31, ic = sub >> 2, jc = sub & 3;
      const int j0 = jc*128, i0 = ic*64;
      const float* WT  = (m == 0) ? a.WThh : (m == 1) ? a.WTpp : a.WTph;
      const float* vec = (m == 2) ? (a.rh + (size_t)(g % 3)*NB*HH) : (a.rp + (size_t)(g & 1)*NB*HH);
      {
        unsigned long long vv[8];
        #pragma unroll
        for (int k = 0; k < 8; k++) {
          int e = tid + k*256;
          int b2 = e >> 6, jl2 = (e & 63)*2;
          vv[k] = ld8u(vec + (size_t)b2*HH + j0 + jl2);
        }
        #pragma unroll
        for (int k = 0; k < 8; k++) {
          int e = tid + k*256;
          int b2 = e >> 6, jl2 = (e & 63)*2;
          vl[jl2*33 + b2]       = u8lo(vv[k]);
          vl[(jl2 + 1)*33 + b2] = u8hi(vv[k]);
        }
      }
      __syncthreads();
      const int bb = tid & 31, ig = tid >> 5;
      const int ii = i0 + ig*8;
      float acc[8] = {0.f,0.f,0.f,0.f,0.f,0.f,0.f,0.f};
      for (int jl = 0; jl < 128; jl++) {
        float v = vl[jl*33 + bb];
        const float* wr = WT + (size_t)(j0 + jl)*HH + ii;
        #pragma unroll
        for (int qq = 0; qq < 8; qq++) acc[qq] += wr[qq] * v;
      }
      float* dst = a.gpart + (((size_t)(m*NB + bb)*4 + jc)*HH) + ii;
      st8(dst + 0, acc[0], acc[1]);
      st8(dst + 2, acc[2], acc[3]);
      st8(dst + 4, acc[4], acc[5]);
      st8(dst + 6, acc[6], acc[7]);
      __syncthreads();   // protect vl before next-iteration restage
    }
    gridbar(a.gcnt, slot, (2*g + 1)*NBLK);
    // ================= phase 2 =================
    if (bid < 32) {
      // state block: owns batch element b = bid
      const int b = bid;
      {
        float vinp = 0.f;
        if (tid >= NF && tid < NIN) {
          if (tid == NF) vinp = lda(a.rwb + (g & 1)*NB + b);
          else           vinp = lda(a.aselb + ((size_t)((g & 1)*NB + b))*4 + (tid - NF - 1));
        }
        if (tid < NIN)
          inpA[0][tid] = (tid < NF) ? ((t < 16) ? a.X[(size_t)((b*4 + (t >> 2))*NTRI + tri)*NF + tid] : 0.0f)
                                    : vinp;
        __syncthreads();
      }
      // hoisted batched loads for both halves
      float G[2][12], rpc[2], rhc2[2], h1v[2];
      #pragma unroll
      for (int kk = 0; kk < 2; kk++) {
        int ii = tid + kk*256;
        #pragma unroll
        for (int m = 0; m < 3; m++)
          #pragma unroll
          for (int q = 0; q < 4; q++)
            G[kk][m*4 + q] = lda(a.gpart + (((size_t)(m*NB + b)*4 + q)*HH) + ii);
        rpc[kk]  = lda(a.rp + (size_t)(g & 1)*NB*HH + b*HH + ii);
        rhc2[kk] = lda(a.rh + (size_t)(g % 3)*NB*HH + b*HH + ii);
        h1v[kk]  = lda(a.h1 + (size_t)(g & 1)*NB*HH + b*HH + ii);
      }
      unsigned long long scu = ld8u(a.stats + (g & 1)*NB*2 + b*2);
      const float m_cur = u8lo(scu), sd_cur = u8hi(scu);
      float vals[7] = {0.f,0.f,0.f,0.f,0.f,0.f,0.f};
      #pragma unroll
      for (int kk = 0; kk < 2; kk++) {
        int ii = tid + kk*256;
        float gh2 = G[kk][0] + G[kk][1] + G[kk][2] + G[kk][3];
        float gh1 = 0.f;
        #pragma unroll
        for (int k = 0; k < NIN; k++) gh1 += a.WTih_h[k*HH + ii] * inpA[0][k];
        float acth = fminf(fmaxf((SCC*h1v[kk] + gh1 + gh2 - THETAC)*SNLC, 0.f), 10.f);
        float rhn = 0.5f*rhc2[kk] + 0.5f*acth;
        float gp2 = G[kk][4] + G[kk][5] + G[kk][6] + G[kk][7];
        float gp3 = G[kk][8] + G[kk][9] + G[kk][10] + G[kk][11];
        float gp1 = 0.f;
        #pragma unroll
        for (int k = 0; k < NIN; k++) gp1 += a.WTih_p[k*HH + ii] * inpA[0][k];
        float actp = gp1 + gp2 + gp3 + a.Bp[ii];
        float rpn = 0.5f*rpc[kk] + 0.5f*fmaxf(actp, 0.f);
        sta(a.rh + (size_t)((g + 1) % 3)*NB*HH + b*HH + ii, rhn);
        sta(a.rp + (size_t)((g + 1) & 1)*NB*HH + b*HH + ii, (t == 23) ? 0.f : rpn);
        float fv = (rhc2[kk] - m_cur) / sd_cur;
        a.FV[(size_t)(g*NB + b)*HH + ii] = fv;   // private, cached
        rh_l[ii] = rhc2[kk];
        rhn_l[ii] = rhn;
        vals[0] += fv; vals[1] += rhn; vals[2] += rhn*rhn;
        vals[3] += a.Wo[0*HH + ii]*rpn; vals[4] += a.Wo[1*HH + ii]*rpn;
        vals[5] += a.Wo[2*HH + ii]*rpn; vals[6] += a.Wo[3*HH + ii]*rpn;
      }
      {
        const int lane = tid & 63, wv = tid >> 6;
        #pragma unroll
        for (int k = 0; k < 7; k++) {
          float v = vals[k];
          #pragma unroll
          for (int off = 32; off > 0; off >>= 1) v += __shfl_down(v, off, 64);
          if (lane == 0) redm[k*4 + wv] = v;
        }
        __syncthreads();
        #pragma unroll
        for (int k = 0; k < 7; k++)
          vals[k] = redm[k*4] + redm[k*4+1] + redm[k*4+2] + redm[k*4+3];
      }
      float sig = vals[0];
      float m2  = vals[1] / (float)HH;
      float sd2 = sqrtf(vals[2] / (float)HH - m2*m2 + EPSC);
      float L0 = vals[3] + a.Bo[0], L1 = vals[4] + a.Bo[1];
      float L2 = vals[5] + a.Bo[2], L3 = vals[6] + a.Bo[3];
      if (tid == 0) {
        sta(a.sigv + b, sig);
        st8(a.stats + ((g + 1) & 1)*NB*2 + b*2, m2, sd2);
        float sl0 = a.slog[b*4], sl1 = a.slog[b*4+1], sl2 = a.slog[b*4+2], sl3 = a.slog[b*4+3];
        float sp0 = a.sprob[b*4], sp1 = a.sprob[b*4+1], sp2 = a.sprob[b*4+2], sp3 = a.sprob[b*4+3];
        if (t >= 12 && t < 20) {
          sl0 += L0; sl1 += L1; sl2 += L2; sl3 += L3;
          float mx = fmaxf(fmaxf(L0, L1), fmaxf(L2, L3));
          float e0 = expf(L0 - mx), e1 = expf(L1 - mx), e2 = expf(L2 - mx), e3 = expf(L3 - mx);
          float es = e0 + e1 + e2 + e3;
          sp0 += e0/es; sp1 += e1/es; sp2 += e2/es; sp3 += e3/es;
        }
        float rwn, as0, as1, as2, as3;
        if (t == 19) {
          int am = 0; float bv = sp0;
          if (sp1 > bv) { bv = sp1; am = 1; }
          if (sp2 > bv) { bv = sp2; am = 2; }
          if (sp3 > bv) { bv = sp3; am = 3; }
          float corr = a.Y[(size_t)(b*4 + am)*NTRI + tri];
          rwn = (corr > 0.9f) ? 1.f : -1.f;
          as0 = (am == 0) ? 1.f : 0.f; as1 = (am == 1) ? 1.f : 0.f;
          as2 = (am == 2) ? 1.f : 0.f; as3 = (am == 3) ? 1.f : 0.f;
        } else {
          rwn = inpA[0][NF];
          as0 = inpA[0][NF+1]; as1 = inpA[0][NF+2]; as2 = inpA[0][NF+3]; as3 = inpA[0][NF+4];
        }
        if (t == 23) {
          float* o = a.out + (size_t)tri*NB*4 + b*4;
          o[0] = sl0/8.f; o[1] = sl1/8.f; o[2] = sl2/8.f; o[3] = sl3/8.f;
          sl0 = sl1 = sl2 = sl3 = 0.f; sp0 = sp1 = sp2 = sp3 = 0.f;
          rwn = 0.f; as0 = as1 = as2 = as3 = 0.f;
        }
        a.slog[b*4] = sl0; a.slog[b*4+1] = sl1; a.slog[b*4+2] = sl2; a.slog[b*4+3] = sl3;
        a.sprob[b*4] = sp0; a.sprob[b*4+1] = sp1; a.sprob[b*4+2] = sp2; a.sprob[b*4+3] = sp3;
        sta(a.rwb + ((g + 1) & 1)*NB + b, rwn);
        float* an = a.aselb + (size_t)(((g + 1) & 1)*NB + b)*4;
        st8(an + 0, as0, as1);
        st8(an + 2, as2, as3);
      }
      __syncthreads();
      // alpha dots for next step (FV private-cached, rhn_l in LDS)
      {
        const int lane = tid & 63, wv = tid >> 6;
        for (int s = wv; s <= g; s += 4) {
          float p = 0.f;
          if (s < g) {
            const float* V = a.FV + (size_t)(s*NB + b)*HH;
            for (int jj = lane; jj < HH; jj += 64) p += V[jj] * rhn_l[jj];
          } else {
            for (int jj = lane; jj < HH; jj += 64) p += ((rh_l[jj] - m_cur)/sd_cur) * rhn_l[jj];
          }
          #pragma unroll
          for (int off = 32; off > 0; off >>= 1) p += __shfl_down(p, off, 64);
          if (lane == 0) sta(a.alpha + b*GTOT + s, p);
        }
      }
    } else if (bid < 64) {
      // W_e GEMV partials (recompute rp_new; batched paired loads)
      const int hb = bid - 32;
      const int jc = hb >> 2, icc = hb & 3;
      const int j0 = jc*64;
      // stage all inp rows (round-3 pattern)
      for (int e = tid; e < NB*NIN; e += 256) {
        int b2 = e / NIN, k = e % NIN;
        float v;
        if (k < NF)       v = (t < 16) ? a.X[(size_t)((b2*4 + (t >> 2))*NTRI + tri)*NF + k] : 0.0f;
        else if (k == NF) v = lda(a.rwb + (g & 1)*NB + b2);
        else              v = lda(a.aselb + ((size_t)((g & 1)*NB + b2))*4 + (k - NF - 1));
        inpA[b2][k] = v;
      }
      __syncthreads();
      #pragma unroll
      for (int r2 = 0; r2 < 2; r2++) {
        int f4i = tid + r2*256;
        int b2 = f4i >> 4, jl4 = (f4i & 15)*4;
        int jj0 = j0 + jl4;
        // hoisted: 8 gpart runs (m=1,2 x q=0..3) x 2 pairs + rp 2 pairs
        unsigned long long Aq[8][2], Rq[2];
        #pragma unroll
        for (int q = 0; q < 8; q++) {
          const float* gp = a.gpart + (((size_t)((1 + (q >> 2))*NB + b2)*4 + (q & 3))*HH) + jj0;
          Aq[q][0] = ld8u(gp);
          Aq[q][1] = ld8u(gp + 2);
        }
        {
          const float* rpp = a.rp + (size_t)(g & 1)*NB*HH + b2*HH + jj0;
          Rq[0] = ld8u(rpp);
          Rq[1] = ld8u(rpp + 2);
        }
        #pragma unroll
        for (int r = 0; r < 4; r++) {
          int jj = jj0 + r;
          const int h = r >> 1;
          float a0 = (r & 1) ? u8hi(Aq[0][h]) : u8lo(Aq[0][h]);
          float a1 = (r & 1) ? u8hi(Aq[1][h]) : u8lo(Aq[1][h]);
          float a2 = (r & 1) ? u8hi(Aq[2][h]) : u8lo(Aq[2][h]);
          float a3 = (r & 1) ? u8hi(Aq[3][h]) : u8lo(Aq[3][h]);
          float b0 = (r & 1) ? u8hi(Aq[4][h]) : u8lo(Aq[4][h]);
          float b1 = (r & 1) ? u8hi(Aq[5][h]) : u8lo(Aq[5][h]);
          float b2f = (r & 1) ? u8hi(Aq[6][h]) : u8lo(Aq[6][h]);
          float b3 = (r & 1) ? u8hi(Aq[7][h]) : u8lo(Aq[7][h]);
          float rv = (r & 1) ? u8hi(Rq[h]) : u8lo(Rq[h]);
          float gp2 = a0 + a1 + a2 + a3;
          float gp3 = b0 + b1 + b2f + b3;
          float gp1 = 0.f;
          #pragma unroll
          for (int k = 0; k < NIN; k++) gp1 += a.WTih_p[k*HH + jj] * inpA[b2][k];
          float actp = gp1 + gp2 + gp3 + a.Bp[jj];
          vl[(jl4 + r)*33 + b2] = 0.5f*rv + 0.5f*fmaxf(actp, 0.f);
        }
      }
      __syncthreads();
      const int bb = tid & 31, ig = tid >> 5;
      const int ii = icc*128 + ig*16;
      float acc[16];
      #pragma unroll
      for (int q = 0; q < 16; q++) acc[q] = 0.f;
      for (int jl = 0; jl < 64; jl++) {
        float v = vl[jl*33 + bb];
        const float* wr = a.WTe + (size_t)(j0 + jl)*HH + ii;
        #pragma unroll
        for (int q = 0; q < 16; q++) acc[q] += wr[q] * v;
      }
      float* dst = a.hepart + ((size_t)bb*8 + jc)*HH + ii;
      #pragma unroll
      for (int q = 0; q < 8; q++) st8(dst + 2*q, acc[2*q], acc[2*q + 1]);
      __syncthreads();   // protect vl before next restage
    }
    gridbar(a.gcnt, slot, (2*g + 2)*NBLK);
  }
}

extern "C" void kernel_launch(void* const* d_in, const int* in_sizes, int n_in,
                              void* d_out, int out_size, void* d_ws, size_t ws_size,
                              hipStream_t stream) {
  (void)in_sizes; (void)n_in; (void)out_size; (void)ws_size;
  Args a;
  a.X     = (const float*)d_in[0];
  a.Y     = (const float*)d_in[1];
  a.A     = (const float*)d_in[2];
  a.RH0   = (const float*)d_in[3];
  a.Wihp  = (const float*)d_in[5];
  a.Whhp  = (const float*)d_in[6];
  a.Bp    = (const float*)d_in[7];
  a.Wh2hp = (const float*)d_in[8];
  a.Wihh  = (const float*)d_in[9];
  a.Wh2hh = (const float*)d_in[10];
  a.Lp    = (const float*)d_in[11];
  a.We    = (const float*)d_in[12];
  a.Be    = (const float*)d_in[13];
  a.Wpe   = (const float*)d_in[14];
  a.Bpe   = (const float*)d_in[15];
  a.Wo    = (const float*)d_in[16];
  a.Bo    = (const float*)d_in[17];
  char* w = (char*)d_ws;
  auto take = [&](size_t n) { char* p = w; w += (n + 255) & ~(size_t)255; return p; };
  a.A0T    = (bf16*)take((size_t)NB*HH*HH*sizeof(bf16));
  a.WThh   = (float*)take((size_t)HH*HH*4);
  a.WTpp   = (float*)take((size_t)HH*HH*4);
  a.WTph   = (float*)take((size_t)HH*HH*4);
  a.WTe    = (float*)take((size_t)HH*HH*4);
  a.WTih_h = (float*)take((size_t)NIN*HH*4);
  a.WTih_p = (float*)take((size_t)NIN*HH*4);
  a.rh     = (float*)take((size_t)3*NB*HH*4);
  a.rp     = (float*)take((size_t)2*NB*HH*4);
  a.h1     = (float*)take((size_t)2*NB*HH*4);
  a.Wp     = (float*)take((size_t)NB*HH*4);
  a.FU     = (float*)take((size_t)GTOT*NB*HH*4);
  a.FV     = (float*)take((size_t)GTOT*NB*HH*4);
  a.alpha  = (float*)take((size_t)NB*GTOT*4);
  a.gpart  = (float*)take((size_t)12*NB*HH*4);
  a.hepart = (float*)take((size_t)8*NB*HH*4);
  a.stats  = (float*)take((size_t)2*NB*2*4);
  a.sigv   = (float*)take((size_t)NB*4);
  a.rwb    = (float*)take((size_t)2*NB*4);
  a.aselb  = (float*)take((size_t)2*NB*4*4);
  a.slog   = (float*)take((size_t)NB*4*4);
  a.sprob  = (float*)take((size_t)NB*4*4);
  a.gcnt   = (int*)take(8*64);
  a.out    = (float*)d_out;
  k_prep_t<<<dim3(9216), dim3(256), 0, stream>>>(a);
  k_prep_i<<<dim3(163),  dim3(256), 0, stream>>>(a);
  k_loop<<<dim3(NBLK), dim3(256), 0, stream>>>(a);
}